// Round 16
// baseline (271.101 us; speedup 1.0000x reference)
//
#include <hip/hip_runtime.h>
#include <math.h>

#define B_  8
#define C_  512
#define N_  3136
#define IC_ 256
#define NPART 784   // 49 nblk * 8 b * 2 wn

typedef __attribute__((ext_vector_type(8))) short bf16x8;
typedef __attribute__((ext_vector_type(4))) float f32x4;
typedef __attribute__((ext_vector_type(16))) float f32x16;

static __device__ __forceinline__ unsigned short f2bf(float f) {
    unsigned int u = __builtin_bit_cast(unsigned int, f);
    u = (u + 0x7fffu + ((u >> 16) & 1u)) >> 16;   // RNE
    return (unsigned short)u;
}
static __device__ __forceinline__ float bf2f(unsigned short u) {
    return __builtin_bit_cast(float, (unsigned int)u << 16);
}
static __device__ __forceinline__ unsigned int pk2(float a, float b) {
    return (unsigned int)f2bf(a) | ((unsigned int)f2bf(b) << 16);
}

// async global->LDS, 16B per lane (dest = wave-uniform base + lane*16).
static __device__ __forceinline__ void gll16(const unsigned short* g, unsigned short* l) {
    __builtin_amdgcn_global_load_lds(
        (const __attribute__((address_space(1))) unsigned int*)g,
        (__attribute__((address_space(3))) unsigned int*)l, 16, 0, 0);
}

// merge two KV-split partial fragments (plane stride N_*IC_) with coeffs
static __device__ __forceinline__ bf16x8 merge8(const unsigned short* pa, float ca, float cb) {
    const bf16x8 va = *(const bf16x8*)pa;
    const bf16x8 vb = *(const bf16x8*)(pa + (size_t)N_ * IC_);
    unsigned int w[4];
#pragma unroll
    for (int k = 0; k < 4; ++k) {
        const float lo = bf2f((unsigned short)va[2 * k])     * ca + bf2f((unsigned short)vb[2 * k])     * cb;
        const float hi = bf2f((unsigned short)va[2 * k + 1]) * ca + bf2f((unsigned short)vb[2 * k + 1]) * cb;
        w[k] = pk2(lo, hi);
    }
    uint4 u; u.x = w[0]; u.y = w[1]; u.z = w[2]; u.w = w[3];
    return __builtin_bit_cast(bf16x8, u);
}

// ---------------------------------------------------------------------------
// Kernel 0a: x [B,C,N] f32  ->  xb [B,N,C] bf16  (LDS transpose, pad 72)
// ---------------------------------------------------------------------------
__global__ __launch_bounds__(256) void xpose_kernel(
    const float* __restrict__ x, unsigned short* __restrict__ xb)
{
    const int n0 = blockIdx.x * 64;
    const int c0 = blockIdx.y * 64;
    const int b  = blockIdx.z;
    __shared__ unsigned short T[64][72];   // T[n][c]
    const int tid = threadIdx.x;
#pragma unroll
    for (int e = 0; e < 4; ++e) {
        const int idx = tid + e * 256;
        const int row = idx >> 4;
        const int c4  = idx & 15;
        const float4 v = *(const float4*)&x[((size_t)b * C_ + c0 + row) * N_ + n0 + c4 * 4];
        T[c4 * 4 + 0][row] = f2bf(v.x);
        T[c4 * 4 + 1][row] = f2bf(v.y);
        T[c4 * 4 + 2][row] = f2bf(v.z);
        T[c4 * 4 + 3][row] = f2bf(v.w);
    }
    __syncthreads();
#pragma unroll
    for (int e = 0; e < 2; ++e) {
        const int s  = tid + e * 256;
        const int nr = s >> 3;
        const int sl = s & 7;
        *(bf16x8*)&xb[((size_t)b * N_ + n0 + nr) * C_ + c0 + sl * 8] =
            *(const bf16x8*)&T[nr][sl * 8];
    }
}

// ---------------------------------------------------------------------------
// Kernel 0b: weight conversion -> Wcat[768][512] bf16 (theta|phi|g), wzwb bf16
// ---------------------------------------------------------------------------
__global__ __launch_bounds__(256) void wconv_kernel(
    const float* __restrict__ tw, const float* __restrict__ pw,
    const float* __restrict__ gw, const float* __restrict__ wzw,
    unsigned short* __restrict__ Wcat, unsigned short* __restrict__ wzwb)
{
    const int gid = blockIdx.x * 256 + threadIdx.x;
    if (gid < 98304) {
        const int i  = gid >> 7;
        const int c4 = gid & 127;
        const float* src = (i < 256) ? &tw[(size_t)i * 512]
                         : (i < 512) ? &pw[(size_t)(i - 256) * 512]
                                     : &gw[(size_t)(i - 512) * 512];
        const float4 v = *(const float4*)&src[c4 * 4];
        ushort4 o; o.x = f2bf(v.x); o.y = f2bf(v.y); o.z = f2bf(v.z); o.w = f2bf(v.w);
        *(ushort4*)&Wcat[(size_t)i * 512 + c4 * 4] = o;
    } else {
        const int g2 = gid - 98304;
        const int r  = g2 >> 6;
        const int c4 = g2 & 63;
        const float4 v = *(const float4*)&wzw[(size_t)r * 256 + c4 * 4];
        ushort4 o; o.x = f2bf(v.x); o.y = f2bf(v.y); o.z = f2bf(v.z); o.w = f2bf(v.w);
        *(ushort4*)&wzwb[(size_t)r * 256 + c4 * 4] = o;
    }
}

// ---------------------------------------------------------------------------
// Kernel 1: QKV projection, MFMA (round-14 numerics: Q unscaled).
// ---------------------------------------------------------------------------
__global__ __launch_bounds__(256, 2) void qkv_mfma_kernel(
    const unsigned short* __restrict__ xb, const unsigned short* __restrict__ Wcat,
    const float* __restrict__ tb, const float* __restrict__ pb,
    const float* __restrict__ gb,
    unsigned short* __restrict__ Q, unsigned short* __restrict__ K,
    unsigned short* __restrict__ Vt)
{
    const int n0 = blockIdx.x * 64;
    const int by = blockIdx.y;
    const int b  = blockIdx.z;
    const int i0 = by * 128;
    const int tid = threadIdx.x;
    const int wq = tid >> 6, lane = tid & 63;
    const int g = lane >> 4, c = lane & 15;
    const int wm = wq >> 1, wn = wq & 1;

    __shared__ unsigned short smem[12288];
    unsigned short* Asm = smem;
    unsigned short* Bsm = smem + 4096;

    const int srow = tid >> 3;
    const int ssl  = tid & 7;

    f32x4 acc[2][4];
#pragma unroll
    for (int mb = 0; mb < 2; ++mb)
#pragma unroll
        for (int nb = 0; nb < 4; ++nb) acc[mb][nb] = (f32x4){0.f, 0.f, 0.f, 0.f};

    bf16x8 ast[2], bst[4];
#pragma unroll
    for (int e = 0; e < 2; ++e) {
        const int row = srow + e * 32;
        ast[e] = *(const bf16x8*)&xb[((size_t)b * N_ + n0 + row) * C_ + ((ssl ^ (row & 7)) << 3)];
    }
#pragma unroll
    for (int e = 0; e < 4; ++e) {
        const int row = srow + e * 32;
        bst[e] = *(const bf16x8*)&Wcat[(size_t)(i0 + row) * C_ + ((ssl ^ (row & 7)) << 3)];
    }
#pragma unroll
    for (int e = 0; e < 2; ++e) *(bf16x8*)&Asm[(srow + e * 32) * 64 + ssl * 8] = ast[e];
#pragma unroll
    for (int e = 0; e < 4; ++e) *(bf16x8*)&Bsm[(srow + e * 32) * 64 + ssl * 8] = bst[e];
    __syncthreads();

    const int arow[2] = { wm * 32 + c, wm * 32 + 16 + c };
    const int brow[4] = { wn * 64 + c, wn * 64 + 16 + c, wn * 64 + 32 + c, wn * 64 + 48 + c };

    for (int s = 0; s < 8; ++s) {
        const int c0n = (s < 7) ? (s + 1) * 64 : s * 64;
#pragma unroll
        for (int e = 0; e < 2; ++e) {
            const int row = srow + e * 32;
            ast[e] = *(const bf16x8*)&xb[((size_t)b * N_ + n0 + row) * C_ + c0n + ((ssl ^ (row & 7)) << 3)];
        }
#pragma unroll
        for (int e = 0; e < 4; ++e) {
            const int row = srow + e * 32;
            bst[e] = *(const bf16x8*)&Wcat[(size_t)(i0 + row) * C_ + c0n + ((ssl ^ (row & 7)) << 3)];
        }
#pragma unroll
        for (int ks = 0; ks < 2; ++ks) {
            bf16x8 af[2], bfr[4];
            const int sl = ((ks << 2) | g);
#pragma unroll
            for (int mb = 0; mb < 2; ++mb)
                af[mb] = *(const bf16x8*)&Asm[arow[mb] * 64 + ((sl ^ (c & 7)) << 3)];
#pragma unroll
            for (int nb = 0; nb < 4; ++nb)
                bfr[nb] = *(const bf16x8*)&Bsm[brow[nb] * 64 + ((sl ^ (c & 7)) << 3)];
#pragma unroll
            for (int mb = 0; mb < 2; ++mb)
#pragma unroll
                for (int nb = 0; nb < 4; ++nb)
                    acc[mb][nb] = __builtin_amdgcn_mfma_f32_16x16x32_bf16(af[mb], bfr[nb], acc[mb][nb], 0, 0, 0);
        }
        __syncthreads();
#pragma unroll
        for (int e = 0; e < 2; ++e) *(bf16x8*)&Asm[(srow + e * 32) * 64 + ssl * 8] = ast[e];
#pragma unroll
        for (int e = 0; e < 4; ++e) *(bf16x8*)&Bsm[(srow + e * 32) * 64 + ssl * 8] = bst[e];
        __syncthreads();
    }

    const int proj = by >> 1;
    const float* bias = (proj == 0) ? tb : (proj == 1) ? pb : gb;
    const int icb = (by & 1) * 128;
    if (proj < 2) {
        unsigned short* out = (proj == 0) ? Q : K;
#pragma unroll
        for (int mb = 0; mb < 2; ++mb)
#pragma unroll
            for (int nb = 0; nb < 4; ++nb)
#pragma unroll
                for (int r = 0; r < 4; ++r) {
                    const int token = n0 + wm * 32 + mb * 16 + g * 4 + r;
                    const int ic = icb + wn * 64 + nb * 16 + c;
                    out[((size_t)b * N_ + token) * IC_ + ic] = f2bf(acc[mb][nb][r] + bias[ic]);
                }
    } else {
        unsigned short* T = smem;
#pragma unroll
        for (int mb = 0; mb < 2; ++mb)
#pragma unroll
            for (int nb = 0; nb < 4; ++nb)
#pragma unroll
                for (int r = 0; r < 4; ++r) {
                    const int il = wn * 64 + nb * 16 + c;
                    const int tl = wm * 32 + mb * 16 + g * 4 + r;
                    T[il * 72 + tl] = f2bf(acc[mb][nb][r] + bias[icb + il]);
                }
        __syncthreads();
#pragma unroll
        for (int e = 0; e < 4; ++e) {
            const int row = (tid >> 3) + e * 32;
            *(bf16x8*)&Vt[((size_t)b * IC_ + icb + row) * N_ + n0 + ((tid & 7) * 8)] =
                *(const bf16x8*)&T[row * 72 + (tid & 7) * 8];
        }
    }
}

// ---------------------------------------------------------------------------
// Kernel 2: MFMA flash attention v9 (proven config; natural-e softmax,
// round-14 numerics restored — base-2 variant crossed the error threshold).
// ---------------------------------------------------------------------------
__global__ __launch_bounds__(512, 2) void attn_kernel(
    const unsigned short* __restrict__ Q, const unsigned short* __restrict__ K,
    const unsigned short* __restrict__ Vt,
    unsigned short* __restrict__ part, float2* __restrict__ ml)
{
    const int b     = blockIdx.x;
    const int qb    = blockIdx.y;
    const int split = blockIdx.z;
    int q0 = qb * 256; if (q0 > N_ - 256) q0 = N_ - 256;   // qb=12 overlap rows identical
    const int t0 = split ? 25 : 0;
    const int t1 = split ? 49 : 25;

    const int tid  = threadIdx.x;
    const int wq   = tid >> 6;       // 0..7
    const int lane = tid & 63;
    const int ql   = lane & 31;      // this lane's q (and d-col for V)
    const int h    = lane >> 5;      // half
    const int swz0 = (ql & 7) ^ (ql >> 3);

    const unsigned short* Qb = Q  + (size_t)b * N_ * IC_;
    const unsigned short* Kb = K  + (size_t)b * N_ * IC_;
    const unsigned short* Vb = Vt + (size_t)b * IC_ * N_;

    __shared__ unsigned short Ks[2][64 * 256];   // 2 x 32 KB, rows=key (512B)
    __shared__ unsigned short Vs[2][256 * 64];   // 2 x 32 KB, rows=d (128B)

    // staging (pre-swizzled global slots; V swizzle is e-invariant, K is not)
    const int krow = tid >> 5, ksl = tid & 31;   // K: rows +16/e
    const int vrow = tid >> 3, vsl = tid & 7;    // V: rows +64/e (row>>3 &7 invariant)
    const unsigned short* vg =
        Vb + (size_t)vrow * N_ + ((vsl ^ ((vrow & 7) ^ ((vrow >> 3) & 7))) << 3);

#define STAGE(buf, t)                                                            \
    {                                                                            \
        _Pragma("unroll") for (int e = 0; e < 4; ++e) {                          \
            const int kr = krow + e * 16;                                        \
            gll16(Kb + ((size_t)(t) * 64 + kr) * IC_ +                           \
                      ((ksl ^ ((kr & 7) ^ ((kr >> 3) & 7))) << 3),               \
                  &Ks[buf][(tid + e * 512) * 8]);                                \
        }                                                                        \
        const unsigned short* vgp = vg + (size_t)(t) * 64;                       \
        _Pragma("unroll") for (int e = 0; e < 4; ++e)                            \
            gll16(vgp + (size_t)e * 64 * N_, &Vs[buf][(tid + e * 512) * 8]);     \
    }

    // hoist Q fragments: B-operand, col=ql, d-slice per step
    bf16x8 qf[16];
    {
        const unsigned short* qrow = &Qb[(size_t)(q0 + wq * 32 + ql) * IC_ + h * 8];
#pragma unroll
        for (int s = 0; s < 16; ++s) qf[s] = *(const bf16x8*)&qrow[s * 16];
    }

    f32x16 yacc[8];
#pragma unroll
    for (int db = 0; db < 8; ++db)
#pragma unroll
        for (int i = 0; i < 16; ++i) yacc[db][i] = 0.f;
    float m = -1e30f, lsum = 0.f;

    STAGE(0, t0);
    asm volatile("s_waitcnt vmcnt(0)" ::: "memory");
    __syncthreads();

    for (int t = t0; t < t1; ++t) {
        const int cur = (t - t0) & 1;
        if (t + 1 < t1) STAGE(cur ^ 1, t + 1);

        // ---- QK^T: S^T[64k][32q] ----
        f32x16 s0, s1;
#pragma unroll
        for (int i = 0; i < 16; ++i) { s0[i] = 0.f; s1[i] = 0.f; }
        __builtin_amdgcn_s_setprio(1);
#pragma unroll
        for (int s = 0; s < 16; ++s) {
            const int sl = ((2 * s + h) ^ swz0) << 3;
            const bf16x8 kf0 = *(const bf16x8*)&Ks[cur][(size_t)ql * 256 + sl];
            s0 = __builtin_amdgcn_mfma_f32_32x32x16_bf16(kf0, qf[s], s0, 0, 0, 0);
            const bf16x8 kf1 = *(const bf16x8*)&Ks[cur][(size_t)(32 + ql) * 256 + (sl ^ 32)];
            s1 = __builtin_amdgcn_mfma_f32_32x32x16_bf16(kf1, qf[s], s1, 0, 0, 0);
        }
        __builtin_amdgcn_s_setprio(0);

        // ---- online softmax (lane owns q=ql; tree reductions) ----
        float mx[16];
#pragma unroll
        for (int i = 0; i < 16; ++i) mx[i] = fmaxf(s0[i], s1[i]);
#pragma unroll
        for (int off = 8; off > 0; off >>= 1)
#pragma unroll
            for (int i = 0; i < 8; ++i)
                if (i < off) mx[i] = fmaxf(mx[i], mx[i + off]);
        float rm = fmaxf(mx[0], __shfl_xor(mx[0], 32));

        // defer-max: only rescale when the running max grew by > 8
        if (__any(rm > m + 8.f)) {
            const float mnew  = fmaxf(m, rm);
            const float scale = __expf(m - mnew);
            m = mnew;
            lsum *= scale;
#pragma unroll
            for (int db = 0; db < 8; ++db)
#pragma unroll
                for (int i = 0; i < 16; ++i) yacc[db][i] *= scale;
        }

#pragma unroll
        for (int i = 0; i < 16; ++i) s0[i] = __expf(s0[i] - m);
#pragma unroll
        for (int i = 0; i < 16; ++i) s1[i] = __expf(s1[i] - m);
        float sm[16];
#pragma unroll
        for (int i = 0; i < 16; ++i) sm[i] = s0[i] + s1[i];
#pragma unroll
        for (int off = 8; off > 0; off >>= 1)
#pragma unroll
            for (int i = 0; i < 8; ++i)
                if (i < off) sm[i] += sm[i + off];
        lsum += sm[0] + __shfl_xor(sm[0], 32);

        // pack P to bf16 pairs (k-consecutive within pair)
        unsigned int pk0[8], pk1[8];
#pragma unroll
        for (int w = 0; w < 8; ++w) {
            pk0[w] = pk2(s0[2 * w], s0[2 * w + 1]);
            pk1[w] = pk2(s1[2 * w], s1[2 * w + 1]);
        }

        // ---- PV: Y^T += mfma32(V^T-frag, P-frag) per K-step s (16 keys) ----
#pragma unroll
        for (int s = 0; s < 4; ++s) {
            const unsigned int* u4 = (s >> 1) ? &pk1[4 * (s & 1)] : &pk0[4 * (s & 1)];
            const unsigned int send0 = h ? u4[0] : u4[2];
            const unsigned int send1 = h ? u4[1] : u4[3];
            const unsigned int r0 = (unsigned int)__shfl_xor((int)send0, 32);
            const unsigned int r1 = (unsigned int)__shfl_xor((int)send1, 32);
            uint4 fw;
            fw.x = h ? r0 : u4[0];
            fw.y = h ? r1 : u4[1];
            fw.z = h ? u4[2] : r0;
            fw.w = h ? u4[3] : r1;
            const bf16x8 pf = __builtin_bit_cast(bf16x8, fw);
            const int vsl_r = ((2 * s + h) ^ swz0) << 3;
            __builtin_amdgcn_s_setprio(1);
#pragma unroll
            for (int db = 0; db < 8; ++db) {
                const bf16x8 vf = *(const bf16x8*)
                    &Vs[cur][(size_t)(db * 32 + ql) * 64 + (vsl_r ^ (((db & 1) << 2) << 3))];
                yacc[db] = __builtin_amdgcn_mfma_f32_32x32x16_bf16(vf, pf, yacc[db], 0, 0, 0);
            }
            __builtin_amdgcn_s_setprio(0);
        }

        asm volatile("s_waitcnt vmcnt(0)" ::: "memory");   // t+1 DMA landed
        __syncthreads();                                   // all waves done with cur
    }

    // ---- epilogue: UNNORMALIZED partial + (m,l) ----
    const size_t pbase = (size_t)(b * 2 + split) * N_;
    const int q = q0 + wq * 32 + ql;
    if (h == 0) ml[pbase + q] = make_float2(m, lsum);
#pragma unroll
    for (int db = 0; db < 8; ++db)
#pragma unroll
        for (int rq = 0; rq < 4; ++rq) {
            ushort4 o;
            o.x = f2bf(yacc[db][4 * rq + 0]);
            o.y = f2bf(yacc[db][4 * rq + 1]);
            o.z = f2bf(yacc[db][4 * rq + 2]);
            o.w = f2bf(yacc[db][4 * rq + 3]);
            *(ushort4*)&part[(pbase + q) * IC_ + 32 * db + 8 * rq + 4 * h] = o;
        }
#undef STAGE
}

// ---------------------------------------------------------------------------
// Kernel 3: wz projection with FUSED KV-split merge + BN partial stats.
// Merge coefficients use __expf (identical arithmetic to the old standalone
// merge kernel). Z out bf16.
// ---------------------------------------------------------------------------
__global__ __launch_bounds__(256, 2) void wz_mfma_kernel(
    const unsigned short* __restrict__ part, const float2* __restrict__ ml,
    const unsigned short* __restrict__ wzwb, const float* __restrict__ wzb,
    unsigned short* __restrict__ Z, float2* __restrict__ partial)
{
    const int n0 = blockIdx.x * 64;
    const int c0 = blockIdx.y * 128;
    const int b  = blockIdx.z;
    const int tid = threadIdx.x;
    const int wq = tid >> 6, lane = tid & 63;
    const int g = lane >> 4, c = lane & 15;
    const int wm = wq >> 1, wn = wq & 1;

    __shared__ unsigned short smem[12288];
    unsigned short* Asm = smem;
    unsigned short* Bsm = smem + 8192;

    const int srow = tid >> 3;
    const int ssl  = tid & 7;

    // merge coefficients for this thread's two fixed token rows
    float ca[2], cb[2];
#pragma unroll
    for (int e = 0; e < 2; ++e) {
        const int token = n0 + srow + e * 32;
        const float2 A  = ml[(size_t)(b * 2 + 0) * N_ + token];
        const float2 Bv = ml[(size_t)(b * 2 + 1) * N_ + token];
        const float mm = fmaxf(A.x, Bv.x);
        const float wA = __expf(A.x - mm), wB = __expf(Bv.x - mm);
        const float inv = 1.f / (A.y * wA + Bv.y * wB);
        ca[e] = wA * inv; cb[e] = wB * inv;
    }

    f32x4 acc[4][2];
#pragma unroll
    for (int mb = 0; mb < 4; ++mb)
#pragma unroll
        for (int nb = 0; nb < 2; ++nb) acc[mb][nb] = (f32x4){0.f, 0.f, 0.f, 0.f};

    bf16x8 ast[4], bst[2];
#pragma unroll
    for (int e = 0; e < 4; ++e) {
        const int row = srow + e * 32;
        ast[e] = *(const bf16x8*)&wzwb[(size_t)(c0 + row) * IC_ + ((ssl ^ (row & 7)) << 3)];
    }
#pragma unroll
    for (int e = 0; e < 2; ++e) {
        const int row = srow + e * 32;
        bst[e] = merge8(&part[((size_t)(b * 2) * N_ + n0 + row) * IC_ + ((ssl ^ (row & 7)) << 3)],
                        ca[e], cb[e]);
    }
#pragma unroll
    for (int e = 0; e < 4; ++e) *(bf16x8*)&Asm[(srow + e * 32) * 64 + ssl * 8] = ast[e];
#pragma unroll
    for (int e = 0; e < 2; ++e) *(bf16x8*)&Bsm[(srow + e * 32) * 64 + ssl * 8] = bst[e];
    __syncthreads();

    const int arow[4] = { wm * 64 + c, wm * 64 + 16 + c, wm * 64 + 32 + c, wm * 64 + 48 + c };
    const int brow[2] = { wn * 32 + c, wn * 32 + 16 + c };

    for (int s = 0; s < 4; ++s) {
        const int k0n = (s < 3) ? (s + 1) * 64 : s * 64;
#pragma unroll
        for (int e = 0; e < 4; ++e) {
            const int row = srow + e * 32;
            ast[e] = *(const bf16x8*)&wzwb[(size_t)(c0 + row) * IC_ + k0n + ((ssl ^ (row & 7)) << 3)];
        }
#pragma unroll
        for (int e = 0; e < 2; ++e) {
            const int row = srow + e * 32;
            bst[e] = merge8(&part[((size_t)(b * 2) * N_ + n0 + row) * IC_ + k0n + ((ssl ^ (row & 7)) << 3)],
                            ca[e], cb[e]);
        }
#pragma unroll
        for (int ks = 0; ks < 2; ++ks) {
            bf16x8 af[4], bfr[2];
            const int sl = ((ks << 2) | g);
#pragma unroll
            for (int mb = 0; mb < 4; ++mb)
                af[mb] = *(const bf16x8*)&Asm[arow[mb] * 64 + ((sl ^ (c & 7)) << 3)];
#pragma unroll
            for (int nb = 0; nb < 2; ++nb)
                bfr[nb] = *(const bf16x8*)&Bsm[brow[nb] * 64 + ((sl ^ (c & 7)) << 3)];
#pragma unroll
            for (int mb = 0; mb < 4; ++mb)
#pragma unroll
                for (int nb = 0; nb < 2; ++nb)
                    acc[mb][nb] = __builtin_amdgcn_mfma_f32_16x16x32_bf16(af[mb], bfr[nb], acc[mb][nb], 0, 0, 0);
        }
        __syncthreads();
#pragma unroll
        for (int e = 0; e < 4; ++e) *(bf16x8*)&Asm[(srow + e * 32) * 64 + ssl * 8] = ast[e];
#pragma unroll
        for (int e = 0; e < 2; ++e) *(bf16x8*)&Bsm[(srow + e * 32) * 64 + ssl * 8] = bst[e];
        __syncthreads();
    }

    const int slot = (b * 49 + blockIdx.x) * 2 + wn;
#pragma unroll
    for (int mb = 0; mb < 4; ++mb) {
#pragma unroll
        for (int r = 0; r < 4; ++r) {
            const int cg = c0 + wm * 64 + mb * 16 + g * 4 + r;
            const float bw = wzb[cg];
            const float z0 = acc[mb][0][r] + bw;
            const float z1 = acc[mb][1][r] + bw;
            Z[((size_t)b * C_ + cg) * N_ + n0 + wn * 32 + c]      = f2bf(z0);
            Z[((size_t)b * C_ + cg) * N_ + n0 + wn * 32 + 16 + c] = f2bf(z1);
            float ps = z0 + z1;
            float pq = z0 * z0 + z1 * z1;
#pragma unroll
            for (int off = 1; off <= 8; off <<= 1) {
                ps += __shfl_xor(ps, off);
                pq += __shfl_xor(pq, off);
            }
            if (c == 0) partial[(size_t)cg * NPART + slot] = make_float2(ps, pq);
        }
    }
}

// ---------------------------------------------------------------------------
// Kernel 4: BN finalize — reduce 784 partials per channel (double accum).
// ---------------------------------------------------------------------------
__global__ __launch_bounds__(256) void bn_finalize_kernel(
    const float2* __restrict__ partial, float* __restrict__ stats)
{
    const int c   = blockIdx.x;
    const int tid = threadIdx.x;
    double s = 0.0, q = 0.0;
    for (int i = tid; i < NPART; i += 256) {
        const float2 p = partial[(size_t)c * NPART + i];
        s += p.x; q += p.y;
    }
    __shared__ double ls[256], lq[256];
    ls[tid] = s; lq[tid] = q;
    __syncthreads();
    for (int off = 128; off > 0; off >>= 1) {
        if (tid < off) { ls[tid] += ls[tid + off]; lq[tid] += lq[tid + off]; }
        __syncthreads();
    }
    if (tid == 0) {
        const double M    = (double)B_ * (double)N_;
        const double mean = ls[0] / M;
        const double var  = lq[0] / M - mean * mean;
        stats[c]      = (float)mean;
        stats[C_ + c] = (float)var;
    }
}

// ---------------------------------------------------------------------------
// Kernel 5: BN apply + residual. Z is bf16; x fp32; out fp32.
// ---------------------------------------------------------------------------
__global__ __launch_bounds__(256) void bn_apply_kernel(
    const unsigned short* __restrict__ Z, const float* __restrict__ x,
    const float* __restrict__ stats,
    const float* __restrict__ bnw, const float* __restrict__ bnb,
    float* __restrict__ out)
{
    const size_t total4 = (size_t)B_ * C_ * N_ / 4;
    const size_t i4 = (size_t)blockIdx.x * blockDim.x + threadIdx.x;
    if (i4 >= total4) return;
    const size_t i = i4 * 4;
    const int c = (int)((i / N_) % C_);
    const float mean = stats[c];
    const float var  = stats[C_ + c];
    const float sc = rsqrtf(var + 1e-5f) * bnw[c];
    const float sh = bnb[c] - mean * sc;
    const ushort4 zu = ((const ushort4*)Z)[i4];
    const float4 xv  = ((const float4*)x)[i4];
    float4 o;
    o.x = bf2f(zu.x) * sc + sh + xv.x;
    o.y = bf2f(zu.y) * sc + sh + xv.y;
    o.z = bf2f(zu.z) * sc + sh + xv.z;
    o.w = bf2f(zu.w) * sc + sh + xv.w;
    ((float4*)out)[i4] = o;
}

// ---------------------------------------------------------------------------
extern "C" void kernel_launch(void* const* d_in, const int* in_sizes, int n_in,
                              void* d_out, int out_size, void* d_ws, size_t ws_size,
                              hipStream_t stream)
{
    const float* x   = (const float*)d_in[0];
    const float* tw  = (const float*)d_in[1];
    const float* tb  = (const float*)d_in[2];
    const float* pw  = (const float*)d_in[3];
    const float* pb  = (const float*)d_in[4];
    const float* gw  = (const float*)d_in[5];
    const float* gb  = (const float*)d_in[6];
    const float* wzw = (const float*)d_in[7];
    const float* wzb = (const float*)d_in[8];
    const float* bnw = (const float*)d_in[9];
    const float* bnb = (const float*)d_in[10];
    float* out = (float*)d_out;

    const size_t NIC = (size_t)B_ * N_ * IC_;      // 6,422,528
    const size_t BNC = (size_t)B_ * N_ * C_;       // 12,845,056 (= 2*NIC)
    unsigned short* Qw   = (unsigned short*)d_ws;  // bf16 [B,N,IC]
    unsigned short* Kw   = Qw + NIC;               // bf16 [B,N,IC]
    unsigned short* Vtw  = Kw + NIC;               // bf16 [B,IC,N]
    unsigned short* xbw  = Vtw + NIC;              // bf16 [B,N,C]; dead after qkv ->
    unsigned short* partw = xbw;                   //   attn partials [B*2][N][IC]
    unsigned short* Wcat = xbw + BNC;              // bf16 [768][512]
    unsigned short* wzwb = Wcat + 768 * 512;       // bf16 [512][256]
    float* stats = (float*)(wzwb + 512 * 256);     // 2*C_
    float2* mlw  = (float2*)(stats + 2 * C_);      // [B*2][N] (m,l)
    float2* bnpart = mlw + (size_t)B_ * 2 * N_;    // [C][NPART]
    unsigned short* Zb16 = (unsigned short*)(bnpart + (size_t)C_ * NPART);  // bf16 [B,C,N]

    wconv_kernel<<<512, 256, 0, stream>>>(tw, pw, gw, wzw, Wcat, wzwb);
    xpose_kernel<<<dim3(N_ / 64, C_ / 64, B_), 256, 0, stream>>>(x, xbw);
    qkv_mfma_kernel<<<dim3(N_ / 64, 6, B_), 256, 0, stream>>>(
        xbw, Wcat, tb, pb, gb, Qw, Kw, Vtw);
    attn_kernel<<<dim3(B_, 13, 2), 512, 0, stream>>>(Qw, Kw, Vtw, partw, mlw);
    wz_mfma_kernel<<<dim3(N_ / 64, C_ / 128, B_), 256, 0, stream>>>(
        partw, mlw, wzwb, wzb, Zb16, bnpart);
    bn_finalize_kernel<<<C_, 256, 0, stream>>>(bnpart, stats);
    const int total4 = B_ * C_ * N_ / 4;
    bn_apply_kernel<<<(total4 + 255) / 256, 256, 0, stream>>>(Zb16, x, stats, bnw, bnb, out);
}

// Round 17
// 265.509 us; speedup vs baseline: 1.0211x; 1.0211x over previous
//
#include <hip/hip_runtime.h>
#include <math.h>

#define B_  8
#define C_  512
#define N_  3136
#define IC_ 256
#define NPART 784   // 49 nblk * 8 b * 2 wn

typedef __attribute__((ext_vector_type(8))) short bf16x8;
typedef __attribute__((ext_vector_type(4))) float f32x4;
typedef __attribute__((ext_vector_type(16))) float f32x16;

static __device__ __forceinline__ unsigned short f2bf(float f) {
    unsigned int u = __builtin_bit_cast(unsigned int, f);
    u = (u + 0x7fffu + ((u >> 16) & 1u)) >> 16;   // RNE
    return (unsigned short)u;
}
static __device__ __forceinline__ float bf2f(unsigned short u) {
    return __builtin_bit_cast(float, (unsigned int)u << 16);
}
static __device__ __forceinline__ unsigned int pk2(float a, float b) {
    return (unsigned int)f2bf(a) | ((unsigned int)f2bf(b) << 16);
}

// async global->LDS, 16B per lane (dest = wave-uniform base + lane*16).
static __device__ __forceinline__ void gll16(const unsigned short* g, unsigned short* l) {
    __builtin_amdgcn_global_load_lds(
        (const __attribute__((address_space(1))) unsigned int*)g,
        (__attribute__((address_space(3))) unsigned int*)l, 16, 0, 0);
}

// merge two KV-split partial fragments (plane stride N_*IC_) with coeffs
static __device__ __forceinline__ bf16x8 merge8(const unsigned short* pa, float ca, float cb) {
    const bf16x8 va = *(const bf16x8*)pa;
    const bf16x8 vb = *(const bf16x8*)(pa + (size_t)N_ * IC_);
    unsigned int w[4];
#pragma unroll
    for (int k = 0; k < 4; ++k) {
        const float lo = bf2f((unsigned short)va[2 * k])     * ca + bf2f((unsigned short)vb[2 * k])     * cb;
        const float hi = bf2f((unsigned short)va[2 * k + 1]) * ca + bf2f((unsigned short)vb[2 * k + 1]) * cb;
        w[k] = pk2(lo, hi);
    }
    uint4 u; u.x = w[0]; u.y = w[1]; u.z = w[2]; u.w = w[3];
    return __builtin_bit_cast(bf16x8, u);
}

// ---------------------------------------------------------------------------
// Kernel 0: fused prep. z<8: x [B,C,N] f32 -> xb [B,N,C] bf16 (LDS transpose);
// z==8: weight conversion -> Wcat[768][512] bf16 (theta|phi|g) + wzwb bf16.
// ---------------------------------------------------------------------------
__global__ __launch_bounds__(256) void prep_kernel(
    const float* __restrict__ x, unsigned short* __restrict__ xb,
    const float* __restrict__ tw, const float* __restrict__ pw,
    const float* __restrict__ gw, const float* __restrict__ wzw,
    unsigned short* __restrict__ Wcat, unsigned short* __restrict__ wzwb)
{
    const int tid = threadIdx.x;
    if (blockIdx.z == 8) {
        // ---- wconv plane (grid-stride over 131072 items) ----
        const int slot = blockIdx.y * 49 + blockIdx.x;   // 0..391
        for (int gid = slot * 256 + tid; gid < 131072; gid += 392 * 256) {
            if (gid < 98304) {
                const int i  = gid >> 7;
                const int c4 = gid & 127;
                const float* src = (i < 256) ? &tw[(size_t)i * 512]
                                 : (i < 512) ? &pw[(size_t)(i - 256) * 512]
                                             : &gw[(size_t)(i - 512) * 512];
                const float4 v = *(const float4*)&src[c4 * 4];
                ushort4 o; o.x = f2bf(v.x); o.y = f2bf(v.y); o.z = f2bf(v.z); o.w = f2bf(v.w);
                *(ushort4*)&Wcat[(size_t)i * 512 + c4 * 4] = o;
            } else {
                const int g2 = gid - 98304;
                const int r  = g2 >> 6;
                const int c4 = g2 & 63;
                const float4 v = *(const float4*)&wzw[(size_t)r * 256 + c4 * 4];
                ushort4 o; o.x = f2bf(v.x); o.y = f2bf(v.y); o.z = f2bf(v.z); o.w = f2bf(v.w);
                *(ushort4*)&wzwb[(size_t)r * 256 + c4 * 4] = o;
            }
        }
        return;
    }
    // ---- xpose plane ----
    const int n0 = blockIdx.x * 64;
    const int c0 = blockIdx.y * 64;
    const int b  = blockIdx.z;
    __shared__ unsigned short T[64][72];   // T[n][c]
#pragma unroll
    for (int e = 0; e < 4; ++e) {
        const int idx = tid + e * 256;
        const int row = idx >> 4;
        const int c4  = idx & 15;
        const float4 v = *(const float4*)&x[((size_t)b * C_ + c0 + row) * N_ + n0 + c4 * 4];
        T[c4 * 4 + 0][row] = f2bf(v.x);
        T[c4 * 4 + 1][row] = f2bf(v.y);
        T[c4 * 4 + 2][row] = f2bf(v.z);
        T[c4 * 4 + 3][row] = f2bf(v.w);
    }
    __syncthreads();
#pragma unroll
    for (int e = 0; e < 2; ++e) {
        const int s  = tid + e * 256;
        const int nr = s >> 3;
        const int sl = s & 7;
        *(bf16x8*)&xb[((size_t)b * N_ + n0 + nr) * C_ + c0 + sl * 8] =
            *(const bf16x8*)&T[nr][sl * 8];
    }
}

// ---------------------------------------------------------------------------
// Kernel 1: QKV projection, MFMA. (256,3): ~100 live VGPR fits the 170-reg
// cap, guaranteeing 3 waves/SIMD for this barrier-cadence-bound kernel.
// ---------------------------------------------------------------------------
__global__ __launch_bounds__(256, 3) void qkv_mfma_kernel(
    const unsigned short* __restrict__ xb, const unsigned short* __restrict__ Wcat,
    const float* __restrict__ tb, const float* __restrict__ pb,
    const float* __restrict__ gb,
    unsigned short* __restrict__ Q, unsigned short* __restrict__ K,
    unsigned short* __restrict__ Vt)
{
    const int n0 = blockIdx.x * 64;
    const int by = blockIdx.y;
    const int b  = blockIdx.z;
    const int i0 = by * 128;
    const int tid = threadIdx.x;
    const int wq = tid >> 6, lane = tid & 63;
    const int g = lane >> 4, c = lane & 15;
    const int wm = wq >> 1, wn = wq & 1;

    __shared__ unsigned short smem[12288];
    unsigned short* Asm = smem;
    unsigned short* Bsm = smem + 4096;

    const int srow = tid >> 3;
    const int ssl  = tid & 7;

    f32x4 acc[2][4];
#pragma unroll
    for (int mb = 0; mb < 2; ++mb)
#pragma unroll
        for (int nb = 0; nb < 4; ++nb) acc[mb][nb] = (f32x4){0.f, 0.f, 0.f, 0.f};

    bf16x8 ast[2], bst[4];
#pragma unroll
    for (int e = 0; e < 2; ++e) {
        const int row = srow + e * 32;
        ast[e] = *(const bf16x8*)&xb[((size_t)b * N_ + n0 + row) * C_ + ((ssl ^ (row & 7)) << 3)];
    }
#pragma unroll
    for (int e = 0; e < 4; ++e) {
        const int row = srow + e * 32;
        bst[e] = *(const bf16x8*)&Wcat[(size_t)(i0 + row) * C_ + ((ssl ^ (row & 7)) << 3)];
    }
#pragma unroll
    for (int e = 0; e < 2; ++e) *(bf16x8*)&Asm[(srow + e * 32) * 64 + ssl * 8] = ast[e];
#pragma unroll
    for (int e = 0; e < 4; ++e) *(bf16x8*)&Bsm[(srow + e * 32) * 64 + ssl * 8] = bst[e];
    __syncthreads();

    const int arow[2] = { wm * 32 + c, wm * 32 + 16 + c };
    const int brow[4] = { wn * 64 + c, wn * 64 + 16 + c, wn * 64 + 32 + c, wn * 64 + 48 + c };

    for (int s = 0; s < 8; ++s) {
        const int c0n = (s < 7) ? (s + 1) * 64 : s * 64;
#pragma unroll
        for (int e = 0; e < 2; ++e) {
            const int row = srow + e * 32;
            ast[e] = *(const bf16x8*)&xb[((size_t)b * N_ + n0 + row) * C_ + c0n + ((ssl ^ (row & 7)) << 3)];
        }
#pragma unroll
        for (int e = 0; e < 4; ++e) {
            const int row = srow + e * 32;
            bst[e] = *(const bf16x8*)&Wcat[(size_t)(i0 + row) * C_ + c0n + ((ssl ^ (row & 7)) << 3)];
        }
#pragma unroll
        for (int ks = 0; ks < 2; ++ks) {
            bf16x8 af[2], bfr[4];
            const int sl = ((ks << 2) | g);
#pragma unroll
            for (int mb = 0; mb < 2; ++mb)
                af[mb] = *(const bf16x8*)&Asm[arow[mb] * 64 + ((sl ^ (c & 7)) << 3)];
#pragma unroll
            for (int nb = 0; nb < 4; ++nb)
                bfr[nb] = *(const bf16x8*)&Bsm[brow[nb] * 64 + ((sl ^ (c & 7)) << 3)];
#pragma unroll
            for (int mb = 0; mb < 2; ++mb)
#pragma unroll
                for (int nb = 0; nb < 4; ++nb)
                    acc[mb][nb] = __builtin_amdgcn_mfma_f32_16x16x32_bf16(af[mb], bfr[nb], acc[mb][nb], 0, 0, 0);
        }
        __syncthreads();
#pragma unroll
        for (int e = 0; e < 2; ++e) *(bf16x8*)&Asm[(srow + e * 32) * 64 + ssl * 8] = ast[e];
#pragma unroll
        for (int e = 0; e < 4; ++e) *(bf16x8*)&Bsm[(srow + e * 32) * 64 + ssl * 8] = bst[e];
        __syncthreads();
    }

    const int proj = by >> 1;
    const float* bias = (proj == 0) ? tb : (proj == 1) ? pb : gb;
    const int icb = (by & 1) * 128;
    if (proj < 2) {
        unsigned short* out = (proj == 0) ? Q : K;
#pragma unroll
        for (int mb = 0; mb < 2; ++mb)
#pragma unroll
            for (int nb = 0; nb < 4; ++nb)
#pragma unroll
                for (int r = 0; r < 4; ++r) {
                    const int token = n0 + wm * 32 + mb * 16 + g * 4 + r;
                    const int ic = icb + wn * 64 + nb * 16 + c;
                    out[((size_t)b * N_ + token) * IC_ + ic] = f2bf(acc[mb][nb][r] + bias[ic]);
                }
    } else {
        unsigned short* T = smem;
#pragma unroll
        for (int mb = 0; mb < 2; ++mb)
#pragma unroll
            for (int nb = 0; nb < 4; ++nb)
#pragma unroll
                for (int r = 0; r < 4; ++r) {
                    const int il = wn * 64 + nb * 16 + c;
                    const int tl = wm * 32 + mb * 16 + g * 4 + r;
                    T[il * 72 + tl] = f2bf(acc[mb][nb][r] + bias[icb + il]);
                }
        __syncthreads();
#pragma unroll
        for (int e = 0; e < 4; ++e) {
            const int row = (tid >> 3) + e * 32;
            *(bf16x8*)&Vt[((size_t)b * IC_ + icb + row) * N_ + n0 + ((tid & 7) * 8)] =
                *(const bf16x8*)&T[row * 72 + (tid & 7) * 8];
        }
    }
}

// ---------------------------------------------------------------------------
// Kernel 2: MFMA flash attention v9 (proven config, untouched).
// ---------------------------------------------------------------------------
__global__ __launch_bounds__(512, 2) void attn_kernel(
    const unsigned short* __restrict__ Q, const unsigned short* __restrict__ K,
    const unsigned short* __restrict__ Vt,
    unsigned short* __restrict__ part, float2* __restrict__ ml)
{
    const int b     = blockIdx.x;
    const int qb    = blockIdx.y;
    const int split = blockIdx.z;
    int q0 = qb * 256; if (q0 > N_ - 256) q0 = N_ - 256;   // qb=12 overlap rows identical
    const int t0 = split ? 25 : 0;
    const int t1 = split ? 49 : 25;

    const int tid  = threadIdx.x;
    const int wq   = tid >> 6;       // 0..7
    const int lane = tid & 63;
    const int ql   = lane & 31;      // this lane's q (and d-col for V)
    const int h    = lane >> 5;      // half
    const int swz0 = (ql & 7) ^ (ql >> 3);

    const unsigned short* Qb = Q  + (size_t)b * N_ * IC_;
    const unsigned short* Kb = K  + (size_t)b * N_ * IC_;
    const unsigned short* Vb = Vt + (size_t)b * IC_ * N_;

    __shared__ unsigned short Ks[2][64 * 256];   // 2 x 32 KB, rows=key (512B)
    __shared__ unsigned short Vs[2][256 * 64];   // 2 x 32 KB, rows=d (128B)

    // staging (pre-swizzled global slots; V swizzle is e-invariant, K is not)
    const int krow = tid >> 5, ksl = tid & 31;   // K: rows +16/e
    const int vrow = tid >> 3, vsl = tid & 7;    // V: rows +64/e (row>>3 &7 invariant)
    const unsigned short* vg =
        Vb + (size_t)vrow * N_ + ((vsl ^ ((vrow & 7) ^ ((vrow >> 3) & 7))) << 3);

#define STAGE(buf, t)                                                            \
    {                                                                            \
        _Pragma("unroll") for (int e = 0; e < 4; ++e) {                          \
            const int kr = krow + e * 16;                                        \
            gll16(Kb + ((size_t)(t) * 64 + kr) * IC_ +                           \
                      ((ksl ^ ((kr & 7) ^ ((kr >> 3) & 7))) << 3),               \
                  &Ks[buf][(tid + e * 512) * 8]);                                \
        }                                                                        \
        const unsigned short* vgp = vg + (size_t)(t) * 64;                       \
        _Pragma("unroll") for (int e = 0; e < 4; ++e)                            \
            gll16(vgp + (size_t)e * 64 * N_, &Vs[buf][(tid + e * 512) * 8]);     \
    }

    // hoist Q fragments: B-operand, col=ql, d-slice per step
    bf16x8 qf[16];
    {
        const unsigned short* qrow = &Qb[(size_t)(q0 + wq * 32 + ql) * IC_ + h * 8];
#pragma unroll
        for (int s = 0; s < 16; ++s) qf[s] = *(const bf16x8*)&qrow[s * 16];
    }

    f32x16 yacc[8];
#pragma unroll
    for (int db = 0; db < 8; ++db)
#pragma unroll
        for (int i = 0; i < 16; ++i) yacc[db][i] = 0.f;
    float m = -1e30f, lsum = 0.f;

    STAGE(0, t0);
    asm volatile("s_waitcnt vmcnt(0)" ::: "memory");
    __syncthreads();

    for (int t = t0; t < t1; ++t) {
        const int cur = (t - t0) & 1;
        if (t + 1 < t1) STAGE(cur ^ 1, t + 1);

        // ---- QK^T: S^T[64k][32q] ----
        f32x16 s0, s1;
#pragma unroll
        for (int i = 0; i < 16; ++i) { s0[i] = 0.f; s1[i] = 0.f; }
        __builtin_amdgcn_s_setprio(1);
#pragma unroll
        for (int s = 0; s < 16; ++s) {
            const int sl = ((2 * s + h) ^ swz0) << 3;
            const bf16x8 kf0 = *(const bf16x8*)&Ks[cur][(size_t)ql * 256 + sl];
            s0 = __builtin_amdgcn_mfma_f32_32x32x16_bf16(kf0, qf[s], s0, 0, 0, 0);
            const bf16x8 kf1 = *(const bf16x8*)&Ks[cur][(size_t)(32 + ql) * 256 + (sl ^ 32)];
            s1 = __builtin_amdgcn_mfma_f32_32x32x16_bf16(kf1, qf[s], s1, 0, 0, 0);
        }
        __builtin_amdgcn_s_setprio(0);

        // ---- online softmax (lane owns q=ql; tree reductions) ----
        float mx[16];
#pragma unroll
        for (int i = 0; i < 16; ++i) mx[i] = fmaxf(s0[i], s1[i]);
#pragma unroll
        for (int off = 8; off > 0; off >>= 1)
#pragma unroll
            for (int i = 0; i < 8; ++i)
                if (i < off) mx[i] = fmaxf(mx[i], mx[i + off]);
        float rm = fmaxf(mx[0], __shfl_xor(mx[0], 32));

        // defer-max: only rescale when the running max grew by > 8
        if (__any(rm > m + 8.f)) {
            const float mnew  = fmaxf(m, rm);
            const float scale = __expf(m - mnew);
            m = mnew;
            lsum *= scale;
#pragma unroll
            for (int db = 0; db < 8; ++db)
#pragma unroll
                for (int i = 0; i < 16; ++i) yacc[db][i] *= scale;
        }

#pragma unroll
        for (int i = 0; i < 16; ++i) s0[i] = __expf(s0[i] - m);
#pragma unroll
        for (int i = 0; i < 16; ++i) s1[i] = __expf(s1[i] - m);
        float sm[16];
#pragma unroll
        for (int i = 0; i < 16; ++i) sm[i] = s0[i] + s1[i];
#pragma unroll
        for (int off = 8; off > 0; off >>= 1)
#pragma unroll
            for (int i = 0; i < 8; ++i)
                if (i < off) sm[i] += sm[i + off];
        lsum += sm[0] + __shfl_xor(sm[0], 32);

        // pack P to bf16 pairs (k-consecutive within pair)
        unsigned int pk0[8], pk1[8];
#pragma unroll
        for (int w = 0; w < 8; ++w) {
            pk0[w] = pk2(s0[2 * w], s0[2 * w + 1]);
            pk1[w] = pk2(s1[2 * w], s1[2 * w + 1]);
        }

        // ---- PV: Y^T += mfma32(V^T-frag, P-frag) per K-step s (16 keys) ----
#pragma unroll
        for (int s = 0; s < 4; ++s) {
            const unsigned int* u4 = (s >> 1) ? &pk1[4 * (s & 1)] : &pk0[4 * (s & 1)];
            const unsigned int send0 = h ? u4[0] : u4[2];
            const unsigned int send1 = h ? u4[1] : u4[3];
            const unsigned int r0 = (unsigned int)__shfl_xor((int)send0, 32);
            const unsigned int r1 = (unsigned int)__shfl_xor((int)send1, 32);
            uint4 fw;
            fw.x = h ? r0 : u4[0];
            fw.y = h ? r1 : u4[1];
            fw.z = h ? u4[2] : r0;
            fw.w = h ? u4[3] : r1;
            const bf16x8 pf = __builtin_bit_cast(bf16x8, fw);
            const int vsl_r = ((2 * s + h) ^ swz0) << 3;
            __builtin_amdgcn_s_setprio(1);
#pragma unroll
            for (int db = 0; db < 8; ++db) {
                const bf16x8 vf = *(const bf16x8*)
                    &Vs[cur][(size_t)(db * 32 + ql) * 64 + (vsl_r ^ (((db & 1) << 2) << 3))];
                yacc[db] = __builtin_amdgcn_mfma_f32_32x32x16_bf16(vf, pf, yacc[db], 0, 0, 0);
            }
            __builtin_amdgcn_s_setprio(0);
        }

        asm volatile("s_waitcnt vmcnt(0)" ::: "memory");   // t+1 DMA landed
        __syncthreads();                                   // all waves done with cur
    }

    // ---- epilogue: UNNORMALIZED partial + (m,l) ----
    const size_t pbase = (size_t)(b * 2 + split) * N_;
    const int q = q0 + wq * 32 + ql;
    if (h == 0) ml[pbase + q] = make_float2(m, lsum);
#pragma unroll
    for (int db = 0; db < 8; ++db)
#pragma unroll
        for (int rq = 0; rq < 4; ++rq) {
            ushort4 o;
            o.x = f2bf(yacc[db][4 * rq + 0]);
            o.y = f2bf(yacc[db][4 * rq + 1]);
            o.z = f2bf(yacc[db][4 * rq + 2]);
            o.w = f2bf(yacc[db][4 * rq + 3]);
            *(ushort4*)&part[(pbase + q) * IC_ + 32 * db + 8 * rq + 4 * h] = o;
        }
#undef STAGE
}

// ---------------------------------------------------------------------------
// Kernel 3: wz projection with FUSED KV-split merge + BN partial stats.
// (256,3) for 3 waves/SIMD (audit ~120 VGPR < 170 cap). Z out bf16.
// ---------------------------------------------------------------------------
__global__ __launch_bounds__(256, 3) void wz_mfma_kernel(
    const unsigned short* __restrict__ part, const float2* __restrict__ ml,
    const unsigned short* __restrict__ wzwb, const float* __restrict__ wzb,
    unsigned short* __restrict__ Z, float2* __restrict__ partial)
{
    const int n0 = blockIdx.x * 64;
    const int c0 = blockIdx.y * 128;
    const int b  = blockIdx.z;
    const int tid = threadIdx.x;
    const int wq = tid >> 6, lane = tid & 63;
    const int g = lane >> 4, c = lane & 15;
    const int wm = wq >> 1, wn = wq & 1;

    __shared__ unsigned short smem[12288];
    unsigned short* Asm = smem;
    unsigned short* Bsm = smem + 8192;

    const int srow = tid >> 3;
    const int ssl  = tid & 7;

    // merge coefficients for this thread's two fixed token rows
    float ca[2], cb[2];
#pragma unroll
    for (int e = 0; e < 2; ++e) {
        const int token = n0 + srow + e * 32;
        const float2 A  = ml[(size_t)(b * 2 + 0) * N_ + token];
        const float2 Bv = ml[(size_t)(b * 2 + 1) * N_ + token];
        const float mm = fmaxf(A.x, Bv.x);
        const float wA = __expf(A.x - mm), wB = __expf(Bv.x - mm);
        const float inv = 1.f / (A.y * wA + Bv.y * wB);
        ca[e] = wA * inv; cb[e] = wB * inv;
    }

    f32x4 acc[4][2];
#pragma unroll
    for (int mb = 0; mb < 4; ++mb)
#pragma unroll
        for (int nb = 0; nb < 2; ++nb) acc[mb][nb] = (f32x4){0.f, 0.f, 0.f, 0.f};

    bf16x8 ast[4], bst[2];
#pragma unroll
    for (int e = 0; e < 4; ++e) {
        const int row = srow + e * 32;
        ast[e] = *(const bf16x8*)&wzwb[(size_t)(c0 + row) * IC_ + ((ssl ^ (row & 7)) << 3)];
    }
#pragma unroll
    for (int e = 0; e < 2; ++e) {
        const int row = srow + e * 32;
        bst[e] = merge8(&part[((size_t)(b * 2) * N_ + n0 + row) * IC_ + ((ssl ^ (row & 7)) << 3)],
                        ca[e], cb[e]);
    }
#pragma unroll
    for (int e = 0; e < 4; ++e) *(bf16x8*)&Asm[(srow + e * 32) * 64 + ssl * 8] = ast[e];
#pragma unroll
    for (int e = 0; e < 2; ++e) *(bf16x8*)&Bsm[(srow + e * 32) * 64 + ssl * 8] = bst[e];
    __syncthreads();

    const int arow[4] = { wm * 64 + c, wm * 64 + 16 + c, wm * 64 + 32 + c, wm * 64 + 48 + c };
    const int brow[2] = { wn * 32 + c, wn * 32 + 16 + c };

    for (int s = 0; s < 4; ++s) {
        const int k0n = (s < 3) ? (s + 1) * 64 : s * 64;
#pragma unroll
        for (int e = 0; e < 4; ++e) {
            const int row = srow + e * 32;
            ast[e] = *(const bf16x8*)&wzwb[(size_t)(c0 + row) * IC_ + k0n + ((ssl ^ (row & 7)) << 3)];
        }
#pragma unroll
        for (int e = 0; e < 2; ++e) {
            const int row = srow + e * 32;
            bst[e] = merge8(&part[((size_t)(b * 2) * N_ + n0 + row) * IC_ + k0n + ((ssl ^ (row & 7)) << 3)],
                            ca[e], cb[e]);
        }
#pragma unroll
        for (int ks = 0; ks < 2; ++ks) {
            bf16x8 af[4], bfr[2];
            const int sl = ((ks << 2) | g);
#pragma unroll
            for (int mb = 0; mb < 4; ++mb)
                af[mb] = *(const bf16x8*)&Asm[arow[mb] * 64 + ((sl ^ (c & 7)) << 3)];
#pragma unroll
            for (int nb = 0; nb < 2; ++nb)
                bfr[nb] = *(const bf16x8*)&Bsm[brow[nb] * 64 + ((sl ^ (c & 7)) << 3)];
#pragma unroll
            for (int mb = 0; mb < 4; ++mb)
#pragma unroll
                for (int nb = 0; nb < 2; ++nb)
                    acc[mb][nb] = __builtin_amdgcn_mfma_f32_16x16x32_bf16(af[mb], bfr[nb], acc[mb][nb], 0, 0, 0);
        }
        __syncthreads();
#pragma unroll
        for (int e = 0; e < 4; ++e) *(bf16x8*)&Asm[(srow + e * 32) * 64 + ssl * 8] = ast[e];
#pragma unroll
        for (int e = 0; e < 2; ++e) *(bf16x8*)&Bsm[(srow + e * 32) * 64 + ssl * 8] = bst[e];
        __syncthreads();
    }

    const int slot = (b * 49 + blockIdx.x) * 2 + wn;
#pragma unroll
    for (int mb = 0; mb < 4; ++mb) {
#pragma unroll
        for (int r = 0; r < 4; ++r) {
            const int cg = c0 + wm * 64 + mb * 16 + g * 4 + r;
            const float bw = wzb[cg];
            const float z0 = acc[mb][0][r] + bw;
            const float z1 = acc[mb][1][r] + bw;
            Z[((size_t)b * C_ + cg) * N_ + n0 + wn * 32 + c]      = f2bf(z0);
            Z[((size_t)b * C_ + cg) * N_ + n0 + wn * 32 + 16 + c] = f2bf(z1);
            float ps = z0 + z1;
            float pq = z0 * z0 + z1 * z1;
#pragma unroll
            for (int off = 1; off <= 8; off <<= 1) {
                ps += __shfl_xor(ps, off);
                pq += __shfl_xor(pq, off);
            }
            if (c == 0) partial[(size_t)cg * NPART + slot] = make_float2(ps, pq);
        }
    }
}

// ---------------------------------------------------------------------------
// Kernel 4: BN finalize — reduce 784 partials per channel (double accum).
// ---------------------------------------------------------------------------
__global__ __launch_bounds__(256) void bn_finalize_kernel(
    const float2* __restrict__ partial, float* __restrict__ stats)
{
    const int c   = blockIdx.x;
    const int tid = threadIdx.x;
    double s = 0.0, q = 0.0;
    for (int i = tid; i < NPART; i += 256) {
        const float2 p = partial[(size_t)c * NPART + i];
        s += p.x; q += p.y;
    }
    __shared__ double ls[256], lq[256];
    ls[tid] = s; lq[tid] = q;
    __syncthreads();
    for (int off = 128; off > 0; off >>= 1) {
        if (tid < off) { ls[tid] += ls[tid + off]; lq[tid] += lq[tid + off]; }
        __syncthreads();
    }
    if (tid == 0) {
        const double M    = (double)B_ * (double)N_;
        const double mean = ls[0] / M;
        const double var  = lq[0] / M - mean * mean;
        stats[c]      = (float)mean;
        stats[C_ + c] = (float)var;
    }
}

// ---------------------------------------------------------------------------
// Kernel 5: BN apply + residual. Z is bf16; x fp32; out fp32.
// ---------------------------------------------------------------------------
__global__ __launch_bounds__(256) void bn_apply_kernel(
    const unsigned short* __restrict__ Z, const float* __restrict__ x,
    const float* __restrict__ stats,
    const float* __restrict__ bnw, const float* __restrict__ bnb,
    float* __restrict__ out)
{
    const size_t total4 = (size_t)B_ * C_ * N_ / 4;
    const size_t i4 = (size_t)blockIdx.x * blockDim.x + threadIdx.x;
    if (i4 >= total4) return;
    const size_t i = i4 * 4;
    const int c = (int)((i / N_) % C_);
    const float mean = stats[c];
    const float var  = stats[C_ + c];
    const float sc = rsqrtf(var + 1e-5f) * bnw[c];
    const float sh = bnb[c] - mean * sc;
    const ushort4 zu = ((const ushort4*)Z)[i4];
    const float4 xv  = ((const float4*)x)[i4];
    float4 o;
    o.x = bf2f(zu.x) * sc + sh + xv.x;
    o.y = bf2f(zu.y) * sc + sh + xv.y;
    o.z = bf2f(zu.z) * sc + sh + xv.z;
    o.w = bf2f(zu.w) * sc + sh + xv.w;
    ((float4*)out)[i4] = o;
}

// ---------------------------------------------------------------------------
extern "C" void kernel_launch(void* const* d_in, const int* in_sizes, int n_in,
                              void* d_out, int out_size, void* d_ws, size_t ws_size,
                              hipStream_t stream)
{
    const float* x   = (const float*)d_in[0];
    const float* tw  = (const float*)d_in[1];
    const float* tb  = (const float*)d_in[2];
    const float* pw  = (const float*)d_in[3];
    const float* pb  = (const float*)d_in[4];
    const float* gw  = (const float*)d_in[5];
    const float* gb  = (const float*)d_in[6];
    const float* wzw = (const float*)d_in[7];
    const float* wzb = (const float*)d_in[8];
    const float* bnw = (const float*)d_in[9];
    const float* bnb = (const float*)d_in[10];
    float* out = (float*)d_out;

    const size_t NIC = (size_t)B_ * N_ * IC_;      // 6,422,528
    const size_t BNC = (size_t)B_ * N_ * C_;       // 12,845,056 (= 2*NIC)
    unsigned short* Qw   = (unsigned short*)d_ws;  // bf16 [B,N,IC]
    unsigned short* Kw   = Qw + NIC;               // bf16 [B,N,IC]
    unsigned short* Vtw  = Kw + NIC;               // bf16 [B,IC,N]
    unsigned short* xbw  = Vtw + NIC;              // bf16 [B,N,C]; dead after qkv ->
    unsigned short* partw = xbw;                   //   attn partials [B*2][N][IC]
    unsigned short* Wcat = xbw + BNC;              // bf16 [768][512]
    unsigned short* wzwb = Wcat + 768 * 512;       // bf16 [512][256]
    float* stats = (float*)(wzwb + 512 * 256);     // 2*C_
    float2* mlw  = (float2*)(stats + 2 * C_);      // [B*2][N] (m,l)
    float2* bnpart = mlw + (size_t)B_ * 2 * N_;    // [C][NPART]
    unsigned short* Zb16 = (unsigned short*)(bnpart + (size_t)C_ * NPART);  // bf16 [B,C,N]

    prep_kernel<<<dim3(N_ / 64, C_ / 64, B_ + 1), 256, 0, stream>>>(
        x, xbw, tw, pw, gw, wzw, Wcat, wzwb);
    qkv_mfma_kernel<<<dim3(N_ / 64, 6, B_), 256, 0, stream>>>(
        xbw, Wcat, tb, pb, gb, Qw, Kw, Vtw);
    attn_kernel<<<dim3(B_, 13, 2), 512, 0, stream>>>(Qw, Kw, Vtw, partw, mlw);
    wz_mfma_kernel<<<dim3(N_ / 64, C_ / 128, B_), 256, 0, stream>>>(
        partw, mlw, wzwb, wzb, Zb16, bnpart);
    bn_finalize_kernel<<<C_, 256, 0, stream>>>(bnpart, stats);
    const int total4 = B_ * C_ * N_ / 4;
    bn_apply_kernel<<<(total4 + 255) / 256, 256, 0, stream>>>(Zb16, x, stats, bnw, bnb, out);
}